// Round 1
// baseline (1391.938 us; speedup 1.0000x reference)
//
#include <hip/hip_runtime.h>

#define THREADS 256

// problem sizes
#define Bsz 2
#define HH 128
#define WW 128
#define HWp (HH*WW)        // 16384
#define Ntot (Bsz*HWp)     // 32768
#define HID 256
#define Mm 1728
#define FMC 17
#define W_OFF 98304        // 'out' elements precede 'weights' in d_out

// ws layout (in floats)
#define WEFF_OFF 0
#define WEFF_SZ 16384                       // 2*2*16*64*2*2
#define F1_OFF  (WEFF_OFF + WEFF_SZ)        // relu(conv1): 2*16*128*128
#define F1_SZ   (Bsz*16*HWp)                // 524288
#define FM_OFF  (F1_OFF + F1_SZ)            // fm rows: 32768*17

#define SAST 68   // LDS row stride (floats): 16B-aligned rows + bank rotation

// ---------------- K0: parity-folded conv1 weights ----------------
// weff[pi][pj][oc][ic][u][v] = sum of conv1_w taps that hit source texel (u,v)
__global__ __launch_bounds__(THREADS) void k0_weff(const float* __restrict__ w1,
                                                   float* __restrict__ weff) {
    int t = blockIdx.x * THREADS + threadIdx.x;
    if (t >= 16384) return;
    int v  = t & 1, u = (t >> 1) & 1, ic = (t >> 2) & 63;
    int oc = (t >> 8) & 15, pj = (t >> 12) & 1, pi = (t >> 13) & 1;
    float s = 0.f;
    for (int ki = 0; ki < 3; ++ki) {
        bool okki = pi ? (u ? (ki == 2) : (ki <= 1)) : (u ? (ki >= 1) : (ki == 0));
        if (!okki) continue;
        for (int kj = 0; kj < 3; ++kj) {
            bool okkj = pj ? (v ? (kj == 2) : (kj <= 1)) : (v ? (kj >= 1) : (kj == 0));
            if (okkj) s += w1[((oc * 64 + ic) * 3 + ki) * 3 + kj];
        }
    }
    weff[t] = s;
}

// ---------------- K1: conv1 on upsampled feature + relu ----------------
__global__ __launch_bounds__(THREADS) void k1_conv1(const float* __restrict__ feat,
                                                    const float* __restrict__ weff,
                                                    const float* __restrict__ b1,
                                                    float* __restrict__ f1) {
    int t = blockIdx.x * THREADS + threadIdx.x;
    if (t >= Bsz * 16 * HWp) return;
    int J = t & 127, I = (t >> 7) & 127, oc = (t >> 14) & 15, bb = t >> 18;
    int pi = I & 1, pj = J & 1, r = I >> 1, c = J >> 1;
    int y0 = r - 1 + pi, x0c = c - 1 + pj;
    const float* wp = weff + (((pi * 2 + pj) * 16 + oc) * 64) * 4;
    float acc = b1[oc];
    bool y0ok = (unsigned)y0 < 64u, y1ok = (unsigned)(y0 + 1) < 64u;
    bool x0ok = (unsigned)x0c < 64u, x1ok = (unsigned)(x0c + 1) < 64u;
    for (int ic = 0; ic < 64; ++ic) {
        const float* fb = feat + (bb * 64 + ic) * 4096;
        float w00 = wp[ic * 4 + 0], w01 = wp[ic * 4 + 1];
        float w10 = wp[ic * 4 + 2], w11 = wp[ic * 4 + 3];
        if (y0ok) {
            const float* row = fb + y0 * 64;
            if (x0ok) acc = fmaf(row[x0c], w00, acc);
            if (x1ok) acc = fmaf(row[x0c + 1], w01, acc);
        }
        if (y1ok) {
            const float* row = fb + (y0 + 1) * 64;
            if (x0ok) acc = fmaf(row[x0c], w10, acc);
            if (x1ok) acc = fmaf(row[x0c + 1], w11, acc);
        }
    }
    f1[t] = fmaxf(acc, 0.f);
}

// ---------------- K2: conv2 -> fm rows (ch16 = pos plane 0) ----------------
__global__ __launch_bounds__(THREADS) void k2_conv2_fm(const float* __restrict__ f1,
                                                       const float* __restrict__ w2,
                                                       const float* __restrict__ b2,
                                                       const float* __restrict__ pos,
                                                       float* __restrict__ fm) {
    int t = blockIdx.x * THREADS + threadIdx.x;
    if (t >= Bsz * FMC * HWp) return;
    int J = t & 127, I = (t >> 7) & 127;
    int bc = t >> 14;
    int ch = bc % FMC, bb = bc / FMC;
    int n = bb * HWp + I * 128 + J;
    float val;
    if (ch == 16) {
        val = pos[(I * 128 + J) * 3];
    } else {
        float acc = b2[ch];
        for (int ic = 0; ic < 16; ++ic) {
            const float* fb = f1 + (bb * 16 + ic) * HWp;
            const float* wb = w2 + (ch * 16 + ic) * 9;
            for (int ki = 0; ki < 3; ++ki) {
                int y = I + ki - 1;
                if ((unsigned)y >= 128u) continue;
                const float* row = fb + y * 128;
                for (int kj = 0; kj < 3; ++kj) {
                    int x = J + kj - 1;
                    if ((unsigned)x >= 128u) continue;
                    acc = fmaf(row[x], wb[ki * 3 + kj], acc);
                }
            }
        }
        val = acc;
    }
    fm[n * FMC + ch] = val;
}

// ---------------- K4: fused GEMM1(+relu) + GEMM2 + permuted weights write ----
// one block = 64 consecutive pixel rows; hdn (64x256) in LDS transposed [k][row];
// B staged per 64-col chunk in LDS [k][col]; 4x4 register micro-tile per thread.
__global__ __launch_bounds__(THREADS) void k4_gemm(const float* __restrict__ fm,
                                                   const float* __restrict__ w1g,
                                                   const float* __restrict__ b1g,
                                                   const float* __restrict__ w2g,
                                                   const float* __restrict__ b2g,
                                                   float* __restrict__ dout) {
    extern __shared__ float lds[];
    float* sA  = lds;                      // [256][SAST] hdn^T : [hid k][row]
    float* sB  = lds + HID * SAST;         // [256][SAST] Bchunk: [k][col]
    float* sFM = lds + 2 * HID * SAST;     // [64*17]
    int*   sOB = (int*)(sFM + 64 * FMC);   // [64] per-row output base

    int tid = threadIdx.x;
    int n0 = blockIdx.x * 64;

    // load fm tile
    for (int idx = tid; idx < 64 * FMC; idx += THREADS)
        sFM[idx] = fm[n0 * FMC + idx];
    // per-row permuted output base
    if (tid < 64) {
        int n = n0 + tid;
        int bb = n >> 14, tt = n & 16383, I = tt >> 7, J = tt & 127;
        int s = ((I & 1) << 1) | (J & 1);
        int p = ((I >> 1) << 6) | (J >> 1);
        sOB[tid] = W_OFF + ((bb * 4 + s) * 4096 + p) * Mm;
    }
    __syncthreads();

    // GEMM1: thread `tid` computes hdn[:, j=tid] for all 64 rows
    {
        float wreg[FMC];
        #pragma unroll
        for (int i = 0; i < FMC; ++i) wreg[i] = w1g[tid * FMC + i];
        float bj = b1g[tid];
        for (int r = 0; r < 64; ++r) {
            float s = bj;
            #pragma unroll
            for (int i = 0; i < FMC; ++i) s = fmaf(sFM[r * FMC + i], wreg[i], s);
            sA[tid * SAST + r] = fmaxf(s, 0.f);
        }
    }

    int ty = tid >> 4, tx = tid & 15;
    int ob[4];
    __syncthreads();
    #pragma unroll
    for (int i = 0; i < 4; ++i) ob[i] = sOB[ty * 4 + i];

    for (int mc = 0; mc < 27; ++mc) {
        int m0 = mc * 64;
        __syncthreads();  // previous chunk fully consumed
        // stage B chunk: sB[k][c] = w2g[(m0+c)*256 + k]
        for (int idx = tid; idx < 64 * HID; idx += THREADS) {
            int c = idx & 63, k = idx >> 6;
            sB[k * SAST + c] = w2g[(m0 + c) * HID + k];
        }
        __syncthreads();

        float4 bias4 = *reinterpret_cast<const float4*>(b2g + m0 + (tx << 2));
        float acc[4][4];
        #pragma unroll
        for (int i = 0; i < 4; ++i) {
            acc[i][0] = bias4.x; acc[i][1] = bias4.y;
            acc[i][2] = bias4.z; acc[i][3] = bias4.w;
        }

        #pragma unroll 4
        for (int k = 0; k < HID; ++k) {
            float4 a4 = *reinterpret_cast<const float4*>(sA + k * SAST + (ty << 2));
            float4 b4 = *reinterpret_cast<const float4*>(sB + k * SAST + (tx << 2));
            float av[4] = {a4.x, a4.y, a4.z, a4.w};
            float bv[4] = {b4.x, b4.y, b4.z, b4.w};
            #pragma unroll
            for (int i = 0; i < 4; ++i)
                #pragma unroll
                for (int j = 0; j < 4; ++j)
                    acc[i][j] = fmaf(av[i], bv[j], acc[i][j]);
        }

        #pragma unroll
        for (int i = 0; i < 4; ++i) {
            float4 v;
            v.x = acc[i][0]; v.y = acc[i][1]; v.z = acc[i][2]; v.w = acc[i][3];
            *reinterpret_cast<float4*>(dout + ob[i] + m0 + (tx << 2)) = v;
        }
    }
}

// ---------------- K5: out[b,o,I,J] = sum_k cols[b,p,k] * w_row[k*3+o] --------
__global__ __launch_bounds__(THREADS) void k5_out(const float* __restrict__ x0g,
                                                  float* __restrict__ dout) {
    int tid = threadIdx.x;
    int lane = tid & 63;
    int n = blockIdx.x * 4 + (tid >> 6);
    int bb = n >> 14, tt = n & 16383, I = tt >> 7, J = tt & 127;
    int i = I >> 1, j = J >> 1;
    int s = ((I & 1) << 1) | (J & 1);
    int p = (i << 6) | j;
    const float* wrow = dout + W_OFF + (size_t)((bb * 4 + s) * 4096 + p) * Mm;
    const float* x0b = x0g + bb * 64 * 4096;
    float a0 = 0.f, a1 = 0.f, a2 = 0.f;
    for (int kk = lane; kk < 576; kk += 64) {
        int c = kk / 9, rem = kk - c * 9;
        int ki = rem / 3, kj = rem - ki * 3;
        int y = i + ki - 1, x = j + kj - 1;
        float val = 0.f;
        if ((unsigned)y < 64u && (unsigned)x < 64u) val = x0b[(c * 64 + y) * 64 + x];
        const float* wp = wrow + kk * 3;
        a0 = fmaf(val, wp[0], a0);
        a1 = fmaf(val, wp[1], a1);
        a2 = fmaf(val, wp[2], a2);
    }
    #pragma unroll
    for (int off = 32; off > 0; off >>= 1) {
        a0 += __shfl_down(a0, off, 64);
        a1 += __shfl_down(a1, off, 64);
        a2 += __shfl_down(a2, off, 64);
    }
    if (lane == 0) {
        int base = bb * 3 * HWp + I * 128 + J;
        dout[base]            = a0;
        dout[base + HWp]      = a1;
        dout[base + 2 * HWp]  = a2;
    }
}

extern "C" void kernel_launch(void* const* d_in, const int* in_sizes, int n_in,
                              void* d_out, int out_size, void* d_ws, size_t ws_size,
                              hipStream_t stream) {
    const float* x0      = (const float*)d_in[0];
    const float* feature = (const float*)d_in[1];
    const float* pos     = (const float*)d_in[2];
    // d_in[3] = mask (unused; integer scale -> identity)
    const float* w1      = (const float*)d_in[4];
    const float* b1      = (const float*)d_in[5];
    const float* w2      = (const float*)d_in[6];
    const float* b2      = (const float*)d_in[7];
    const float* f2w1_w  = (const float*)d_in[8];
    const float* f2w1_b  = (const float*)d_in[9];
    const float* f2w2_w  = (const float*)d_in[10];
    const float* f2w2_b  = (const float*)d_in[11];

    float* out = (float*)d_out;
    float* ws  = (float*)d_ws;
    float* weff = ws + WEFF_OFF;
    float* f1   = ws + F1_OFF;
    float* fm   = ws + FM_OFF;

    k0_weff<<<16384 / THREADS, THREADS, 0, stream>>>(w1, weff);
    k1_conv1<<<(Bsz * 16 * HWp) / THREADS, THREADS, 0, stream>>>(feature, weff, b1, f1);
    k2_conv2_fm<<<(Bsz * FMC * HWp) / THREADS, THREADS, 0, stream>>>(f1, w2, b2, pos, fm);

    size_t ldsBytes = (size_t)(2 * HID * SAST + 64 * FMC + 64) * 4;  // 143872 B
    k4_gemm<<<Ntot / 64, THREADS, ldsBytes, stream>>>(fm, f2w1_w, f2w1_b,
                                                      f2w2_w, f2w2_b, out);
    k5_out<<<Ntot / 4, THREADS, 0, stream>>>(x0, out);
}

// Round 2
// 244.561 us; speedup vs baseline: 5.6916x; 5.6916x over previous
//
#include <hip/hip_runtime.h>

#define THREADS 256

// problem sizes
#define Bsz 2
#define HWp 16384          // 128*128
#define Ntot (Bsz*HWp)     // 32768
#define HID 256
#define Mm 1728
#define FMC 17
#define W_OFF 98304        // 'out' elements precede 'weights' in d_out

// ws layout (in floats)
#define WEFF_OFF 0
#define WEFF_SZ 16384
#define F1_OFF  (WEFF_OFF + WEFF_SZ)        // relu(conv1): 2*16*128*128 floats
#define F1_SZ   (Bsz*16*HWp)
#define FM_OFF  (F1_OFF + F1_SZ)            // fm rows: 32768*17 floats
// after k2, the F1 region is dead -> reuse it for bf16 B (1728*256*2 B = 884736 B < 2 MB)

typedef __attribute__((ext_vector_type(8))) short bf16x8;
typedef __attribute__((ext_vector_type(4))) float f32x4;

static __device__ __forceinline__ short f2bf(float x) {
    unsigned u = __builtin_bit_cast(unsigned, x);
    unsigned r = (u + 0x7fff + ((u >> 16) & 1)) >> 16;
    return (short)r;
}

// ---------------- K0: parity-folded conv1 weights ----------------
__global__ __launch_bounds__(THREADS) void k0_weff(const float* __restrict__ w1,
                                                   float* __restrict__ weff) {
    int t = blockIdx.x * THREADS + threadIdx.x;
    if (t >= 16384) return;
    int v  = t & 1, u = (t >> 1) & 1, ic = (t >> 2) & 63;
    int oc = (t >> 8) & 15, pj = (t >> 12) & 1, pi = (t >> 13) & 1;
    float s = 0.f;
    for (int ki = 0; ki < 3; ++ki) {
        bool okki = pi ? (u ? (ki == 2) : (ki <= 1)) : (u ? (ki >= 1) : (ki == 0));
        if (!okki) continue;
        for (int kj = 0; kj < 3; ++kj) {
            bool okkj = pj ? (v ? (kj == 2) : (kj <= 1)) : (v ? (kj >= 1) : (kj == 0));
            if (okkj) s += w1[((oc * 64 + ic) * 3 + ki) * 3 + kj];
        }
    }
    weff[t] = s;
}

// ---------------- K1: conv1 on upsampled feature + relu ----------------
__global__ __launch_bounds__(THREADS) void k1_conv1(const float* __restrict__ feat,
                                                    const float* __restrict__ weff,
                                                    const float* __restrict__ b1,
                                                    float* __restrict__ f1) {
    int t = blockIdx.x * THREADS + threadIdx.x;
    if (t >= Bsz * 16 * HWp) return;
    int J = t & 127, I = (t >> 7) & 127, oc = (t >> 14) & 15, bb = t >> 18;
    int pi = I & 1, pj = J & 1, r = I >> 1, c = J >> 1;
    int y0 = r - 1 + pi, x0c = c - 1 + pj;
    const float* wp = weff + (((pi * 2 + pj) * 16 + oc) * 64) * 4;
    float acc = b1[oc];
    bool y0ok = (unsigned)y0 < 64u, y1ok = (unsigned)(y0 + 1) < 64u;
    bool x0ok = (unsigned)x0c < 64u, x1ok = (unsigned)(x0c + 1) < 64u;
    for (int ic = 0; ic < 64; ++ic) {
        const float* fb = feat + (bb * 64 + ic) * 4096;
        float w00 = wp[ic * 4 + 0], w01 = wp[ic * 4 + 1];
        float w10 = wp[ic * 4 + 2], w11 = wp[ic * 4 + 3];
        if (y0ok) {
            const float* row = fb + y0 * 64;
            if (x0ok) acc = fmaf(row[x0c], w00, acc);
            if (x1ok) acc = fmaf(row[x0c + 1], w01, acc);
        }
        if (y1ok) {
            const float* row = fb + (y0 + 1) * 64;
            if (x0ok) acc = fmaf(row[x0c], w10, acc);
            if (x1ok) acc = fmaf(row[x0c + 1], w11, acc);
        }
    }
    f1[t] = fmaxf(acc, 0.f);
}

// ---------------- K2: conv2 -> fm rows (ch16 = pos plane 0) ----------------
__global__ __launch_bounds__(THREADS) void k2_conv2_fm(const float* __restrict__ f1,
                                                       const float* __restrict__ w2,
                                                       const float* __restrict__ b2,
                                                       const float* __restrict__ pos,
                                                       float* __restrict__ fm) {
    int t = blockIdx.x * THREADS + threadIdx.x;
    if (t >= Bsz * FMC * HWp) return;
    int J = t & 127, I = (t >> 7) & 127;
    int bc = t >> 14;
    int ch = bc % FMC, bb = bc / FMC;
    int n = bb * HWp + I * 128 + J;
    float val;
    if (ch == 16) {
        val = pos[(I * 128 + J) * 3];
    } else {
        float acc = b2[ch];
        for (int ic = 0; ic < 16; ++ic) {
            const float* fb = f1 + (bb * 16 + ic) * HWp;
            const float* wb = w2 + (ch * 16 + ic) * 9;
            for (int ki = 0; ki < 3; ++ki) {
                int y = I + ki - 1;
                if ((unsigned)y >= 128u) continue;
                const float* row = fb + y * 128;
                for (int kj = 0; kj < 3; ++kj) {
                    int x = J + kj - 1;
                    if ((unsigned)x >= 128u) continue;
                    acc = fmaf(row[x], wb[ki * 3 + kj], acc);
                }
            }
        }
        val = acc;
    }
    fm[n * FMC + ch] = val;
}

// ---------------- K3: convert f2w2_w (1728x256 fp32) -> bf16 ----------------
__global__ __launch_bounds__(THREADS) void k3_cvtB(const float* __restrict__ w2g,
                                                   short* __restrict__ wB) {
    int t = blockIdx.x * THREADS + threadIdx.x;
    if (t < Mm * HID) wB[t] = f2bf(w2g[t]);
}

// ---------------- K4: fused GEMM1(+relu) + bf16-MFMA GEMM2 ----------------
// block = 64 rows, 4 waves. hdn -> LDS bf16 (16B-unit transposed layout).
// B-frags loaded straight from global bf16 (L2-resident). Wave w owns
// N-chunks w, w+4, ... (27 chunks of 64 cols); no barriers in main loop.
__global__ __launch_bounds__(THREADS) void k4_gemm(const float* __restrict__ fm,
                                                   const float* __restrict__ w1g,
                                                   const float* __restrict__ b1g,
                                                   const short* __restrict__ wB,
                                                   const float* __restrict__ b2g,
                                                   float* __restrict__ dout) {
    // sA layout (shorts): element (row,k) at ((k>>3)*64 + row)*8 + (k&7)
    __shared__ short sA[16384];     // 32 KB
    __shared__ float sFM[64 * FMC];
    __shared__ int   sOB[64];

    int tid = threadIdx.x;
    int n0 = blockIdx.x * 64;

    for (int idx = tid; idx < 64 * FMC; idx += THREADS)
        sFM[idx] = fm[n0 * FMC + idx];
    if (tid < 64) {
        int n = n0 + tid;
        int bb = n >> 14, tt = n & 16383, I = tt >> 7, J = tt & 127;
        int s = ((I & 1) << 1) | (J & 1);
        int p = ((I >> 1) << 6) | (J >> 1);
        sOB[tid] = W_OFF + ((bb * 4 + s) * 4096 + p) * Mm;
    }
    __syncthreads();

    // GEMM1: thread tid computes hdn[r][k=tid] for all 64 rows -> sA bf16
    {
        float wreg[FMC];
        #pragma unroll
        for (int i = 0; i < FMC; ++i) wreg[i] = w1g[tid * FMC + i];
        float bj = b1g[tid];
        int g = (tid >> 3) & 7;                       // bank-rotation group
        int base = (tid >> 3) * 512 + (tid & 7);      // short index
        for (int rr = 0; rr < 64; ++rr) {
            int r = (rr + g) & 63;
            float s = bj;
            #pragma unroll
            for (int i = 0; i < FMC; ++i) s = fmaf(sFM[r * FMC + i], wreg[i], s);
            sA[base + r * 8] = f2bf(fmaxf(s, 0.f));
        }
    }
    __syncthreads();

    int wid = tid >> 6, l = tid & 63;
    int lm = l & 15, lg = l >> 4;

    // per-lane output row bases: D row = rt*16 + lg*4 + r
    int rowbase[4][4];
    #pragma unroll
    for (int rt = 0; rt < 4; ++rt)
        #pragma unroll
        for (int r = 0; r < 4; ++r)
            rowbase[rt][r] = sOB[rt * 16 + lg * 4 + r];

    // A-frag per-lane base (short index): row=rt*16+lm, k=32s+8lg+i
    //   idx = s*2048 + lg*512 + rt*128 + lm*8 + i
    const short* aptr = sA + lg * 512 + lm * 8;
    // B-frag per-lane base: wB[(col)*256 + k], col = m0+ct*16+lm, k = 32s+8lg+i
    const short* bptr = wB + lm * 256 + lg * 8;

    for (int mc = wid; mc < 27; mc += 4) {
        int m0 = mc * 64;
        f32x4 acc[4][4];
        #pragma unroll
        for (int ct = 0; ct < 4; ++ct) {
            float bias = b2g[m0 + ct * 16 + lm];
            #pragma unroll
            for (int rt = 0; rt < 4; ++rt)
                acc[rt][ct] = (f32x4){bias, bias, bias, bias};
        }
        const short* bp0 = bptr + m0 * HID;
        #pragma unroll 2
        for (int s = 0; s < 8; ++s) {
            bf16x8 af[4], bfr[4];
            #pragma unroll
            for (int rt = 0; rt < 4; ++rt)
                af[rt] = *(const bf16x8*)(aptr + s * 2048 + rt * 128);
            #pragma unroll
            for (int ct = 0; ct < 4; ++ct)
                bfr[ct] = *(const bf16x8*)(bp0 + ct * 16 * HID + s * 32);
            #pragma unroll
            for (int rt = 0; rt < 4; ++rt)
                #pragma unroll
                for (int ct = 0; ct < 4; ++ct)
                    acc[rt][ct] = __builtin_amdgcn_mfma_f32_16x16x32_bf16(
                        af[rt], bfr[ct], acc[rt][ct], 0, 0, 0);
        }
        #pragma unroll
        for (int rt = 0; rt < 4; ++rt)
            #pragma unroll
            for (int ct = 0; ct < 4; ++ct) {
                int cb = m0 + ct * 16 + lm;
                #pragma unroll
                for (int r = 0; r < 4; ++r)
                    dout[rowbase[rt][r] + cb] = acc[rt][ct][r];
            }
    }
}

// ---------------- K5: out[b,o,I,J] = sum_k cols[b,p,k] * w_row[k*3+o] --------
__global__ __launch_bounds__(THREADS) void k5_out(const float* __restrict__ x0g,
                                                  float* __restrict__ dout) {
    int tid = threadIdx.x;
    int lane = tid & 63;
    int n = blockIdx.x * 4 + (tid >> 6);
    int bb = n >> 14, tt = n & 16383, I = tt >> 7, J = tt & 127;
    int i = I >> 1, j = J >> 1;
    int s = ((I & 1) << 1) | (J & 1);
    int p = (i << 6) | j;
    const float* wrow = dout + W_OFF + (size_t)((bb * 4 + s) * 4096 + p) * Mm;
    const float* x0b = x0g + bb * 64 * 4096;
    float a0 = 0.f, a1 = 0.f, a2 = 0.f;
    for (int kk = lane; kk < 576; kk += 64) {
        int c = kk / 9, rem = kk - c * 9;
        int ki = rem / 3, kj = rem - ki * 3;
        int y = i + ki - 1, x = j + kj - 1;
        float val = 0.f;
        if ((unsigned)y < 64u && (unsigned)x < 64u) val = x0b[(c * 64 + y) * 64 + x];
        const float* wp = wrow + kk * 3;
        a0 = fmaf(val, wp[0], a0);
        a1 = fmaf(val, wp[1], a1);
        a2 = fmaf(val, wp[2], a2);
    }
    #pragma unroll
    for (int off = 32; off > 0; off >>= 1) {
        a0 += __shfl_down(a0, off, 64);
        a1 += __shfl_down(a1, off, 64);
        a2 += __shfl_down(a2, off, 64);
    }
    if (lane == 0) {
        int base = bb * 3 * HWp + I * 128 + J;
        dout[base]           = a0;
        dout[base + HWp]     = a1;
        dout[base + 2 * HWp] = a2;
    }
}

extern "C" void kernel_launch(void* const* d_in, const int* in_sizes, int n_in,
                              void* d_out, int out_size, void* d_ws, size_t ws_size,
                              hipStream_t stream) {
    const float* x0      = (const float*)d_in[0];
    const float* feature = (const float*)d_in[1];
    const float* pos     = (const float*)d_in[2];
    const float* w1      = (const float*)d_in[4];
    const float* b1      = (const float*)d_in[5];
    const float* w2      = (const float*)d_in[6];
    const float* b2      = (const float*)d_in[7];
    const float* f2w1_w  = (const float*)d_in[8];
    const float* f2w1_b  = (const float*)d_in[9];
    const float* f2w2_w  = (const float*)d_in[10];
    const float* f2w2_b  = (const float*)d_in[11];

    float* out = (float*)d_out;
    float* ws  = (float*)d_ws;
    float* weff = ws + WEFF_OFF;
    float* f1   = ws + F1_OFF;
    float* fm   = ws + FM_OFF;
    short* wB   = (short*)(ws + F1_OFF);   // reuse F1 region after k2

    k0_weff<<<16384 / THREADS, THREADS, 0, stream>>>(w1, weff);
    k1_conv1<<<(Bsz * 16 * HWp) / THREADS, THREADS, 0, stream>>>(feature, weff, b1, f1);
    k2_conv2_fm<<<(Bsz * FMC * HWp) / THREADS, THREADS, 0, stream>>>(f1, w2, b2, pos, fm);
    k3_cvtB<<<(Mm * HID + THREADS - 1) / THREADS, THREADS, 0, stream>>>(f2w2_w, wB);
    k4_gemm<<<Ntot / 64, THREADS, 0, stream>>>(fm, f2w1_w, f2w1_b, wB, f2w2_b, out);
    k5_out<<<Ntot / 4, THREADS, 0, stream>>>(x0, out);
}

// Round 3
// 177.387 us; speedup vs baseline: 7.8469x; 1.3787x over previous
//
#include <hip/hip_runtime.h>

#define THREADS 256

// problem sizes
#define Bsz 2
#define HWp 16384          // 128*128
#define Ntot (Bsz*HWp)     // 32768
#define HID 256
#define Mm 1728
#define FMC 17
#define W_OFF 98304        // 'out' elements precede 'weights' in d_out

// ws layout (in floats)
#define F1_OFF  16384                       // relu(conv1): 2*16*128*128 floats
#define F1_SZ   (Bsz*16*HWp)
#define FM_OFF  (F1_OFF + F1_SZ)            // fm rows: 32768*17 floats
// after k2, the F1 region is dead -> reuse it for bf16 B (1728*256*2 B)

typedef __attribute__((ext_vector_type(8))) short bf16x8;
typedef __attribute__((ext_vector_type(4))) float f32x4;

static __device__ __forceinline__ short f2bf(float x) {
    unsigned u = __builtin_bit_cast(unsigned, x);
    unsigned r = (u + 0x7fff + ((u >> 16) & 1)) >> 16;
    return (short)r;
}

// ---------------- K1: conv1 on upsampled feature + relu ----------------
// thread = (bb, oc, source pixel r,c) -> computes the 2x2 parity block.
// weff (parity-folded conv1 taps for this block's uniform oc) built in LDS.
__global__ __launch_bounds__(THREADS) void k1_conv1(const float* __restrict__ feat,
                                                    const float* __restrict__ w1,
                                                    const float* __restrict__ b1,
                                                    float* __restrict__ f1) {
    __shared__ float sW[4 * 64 * 4];   // [pp][ic][u*2+v]
    int tid = threadIdx.x;
    int t = blockIdx.x * THREADS + tid;
    int c = t & 63, r = (t >> 6) & 63, oc = (t >> 12) & 15, bb = t >> 16;

    // build weff slice for this oc
    #pragma unroll
    for (int q = 0; q < 4; ++q) {
        int e = tid * 4 + q;
        int v = e & 1, u = (e >> 1) & 1, ic = (e >> 2) & 63, pp = (e >> 8) & 3;
        int pi = pp >> 1, pj = pp & 1;
        float s = 0.f;
        for (int ki = 0; ki < 3; ++ki) {
            bool okki = pi ? (u ? (ki == 2) : (ki <= 1)) : (u ? (ki >= 1) : (ki == 0));
            if (!okki) continue;
            for (int kj = 0; kj < 3; ++kj) {
                bool okkj = pj ? (v ? (kj == 2) : (kj <= 1)) : (v ? (kj >= 1) : (kj == 0));
                if (okkj) s += w1[((oc * 64 + ic) * 3 + ki) * 3 + kj];
            }
        }
        sW[(pp * 64 + ic) * 4 + u * 2 + v] = s;
    }
    __syncthreads();

    float bias = b1[oc];
    float acc00 = bias, acc01 = bias, acc10 = bias, acc11 = bias;

    float my0 = (r > 0) ? 1.f : 0.f, my2 = (r < 63) ? 1.f : 0.f;
    float mx0 = (c > 0) ? 1.f : 0.f, mx2 = (c < 63) ? 1.f : 0.f;
    float m00 = my0 * mx0, m01 = my0, m02 = my0 * mx2;
    float m10 = mx0,       m12 = mx2;
    float m20 = my2 * mx0, m21 = my2, m22 = my2 * mx2;
    int ro0 = (r > 0) ? -64 : 0, ro2 = (r < 63) ? 64 : 0;
    int co0 = (c > 0) ? -1 : 0,  co2 = (c < 63) ? 1 : 0;

    const float* fb = feat + bb * 64 * 4096 + r * 64 + c;
    for (int ic = 0; ic < 64; ++ic) {
        const float* p1 = fb + ic * 4096;
        const float* p0 = p1 + ro0;
        const float* p2 = p1 + ro2;
        float v00 = p0[co0] * m00, v01 = p0[0] * m01, v02 = p0[co2] * m02;
        float v10 = p1[co0] * m10, v11 = p1[0],       v12 = p1[co2] * m12;
        float v20 = p2[co0] * m20, v21 = p2[0] * m21, v22 = p2[co2] * m22;

        f32x4 w0 = *(const f32x4*)(sW + (0 * 64 + ic) * 4);
        f32x4 w1v = *(const f32x4*)(sW + (1 * 64 + ic) * 4);
        f32x4 w2v = *(const f32x4*)(sW + (2 * 64 + ic) * 4);
        f32x4 w3 = *(const f32x4*)(sW + (3 * 64 + ic) * 4);

        // acc[pi][pj] += w[pi*2+pj][u*2+v] * v[pi+u][pj+v]
        acc00 = fmaf(w0[0], v00, acc00); acc00 = fmaf(w0[1], v01, acc00);
        acc00 = fmaf(w0[2], v10, acc00); acc00 = fmaf(w0[3], v11, acc00);
        acc01 = fmaf(w1v[0], v01, acc01); acc01 = fmaf(w1v[1], v02, acc01);
        acc01 = fmaf(w1v[2], v11, acc01); acc01 = fmaf(w1v[3], v12, acc01);
        acc10 = fmaf(w2v[0], v10, acc10); acc10 = fmaf(w2v[1], v11, acc10);
        acc10 = fmaf(w2v[2], v20, acc10); acc10 = fmaf(w2v[3], v21, acc10);
        acc11 = fmaf(w3[0], v11, acc11); acc11 = fmaf(w3[1], v12, acc11);
        acc11 = fmaf(w3[2], v21, acc11); acc11 = fmaf(w3[3], v22, acc11);
    }

    float* fo = f1 + (bb * 16 + oc) * HWp + (2 * r) * 128 + 2 * c;
    float2 r0 = make_float2(fmaxf(acc00, 0.f), fmaxf(acc01, 0.f));
    float2 r1 = make_float2(fmaxf(acc10, 0.f), fmaxf(acc11, 0.f));
    *reinterpret_cast<float2*>(fo) = r0;
    *reinterpret_cast<float2*>(fo + 128) = r1;
}

// ---------------- K2: conv2 -> fm rows (ch16 = pos plane 0) ----------------
__global__ __launch_bounds__(THREADS) void k2_conv2_fm(const float* __restrict__ f1,
                                                       const float* __restrict__ w2,
                                                       const float* __restrict__ b2,
                                                       const float* __restrict__ pos,
                                                       float* __restrict__ fm) {
    int t = blockIdx.x * THREADS + threadIdx.x;
    if (t >= Bsz * FMC * HWp) return;
    int J = t & 127, I = (t >> 7) & 127;
    int bc = t >> 14;
    int ch = bc % FMC, bb = bc / FMC;
    int n = bb * HWp + I * 128 + J;
    float val;
    if (ch == 16) {
        val = pos[(I * 128 + J) * 3];
    } else {
        float acc = b2[ch];
        for (int ic = 0; ic < 16; ++ic) {
            const float* fb = f1 + (bb * 16 + ic) * HWp;
            const float* wb = w2 + (ch * 16 + ic) * 9;
            for (int ki = 0; ki < 3; ++ki) {
                int y = I + ki - 1;
                if ((unsigned)y >= 128u) continue;
                const float* row = fb + y * 128;
                for (int kj = 0; kj < 3; ++kj) {
                    int x = J + kj - 1;
                    if ((unsigned)x >= 128u) continue;
                    acc = fmaf(row[x], wb[ki * 3 + kj], acc);
                }
            }
        }
        val = acc;
    }
    fm[n * FMC + ch] = val;
}

// ---------------- K3: convert f2w2_w (1728x256 fp32) -> bf16 ----------------
__global__ __launch_bounds__(THREADS) void k3_cvtB(const float* __restrict__ w2g,
                                                   short* __restrict__ wB) {
    int t = blockIdx.x * THREADS + threadIdx.x;
    if (t < Mm * HID) wB[t] = f2bf(w2g[t]);
}

// ---------------- K4: fused GEMM1(+relu) + bf16-MFMA GEMM2 ----------------
__global__ __launch_bounds__(THREADS) void k4_gemm(const float* __restrict__ fm,
                                                   const float* __restrict__ w1g,
                                                   const float* __restrict__ b1g,
                                                   const short* __restrict__ wB,
                                                   const float* __restrict__ b2g,
                                                   float* __restrict__ dout) {
    // sA layout (shorts): element (row,k) at ((k>>3)*64 + row)*8 + (k&7)
    __shared__ short sA[16384];       // 32 KB
    __shared__ float sFM[64 * 20];    // padded stride 20
    __shared__ int   sOB[64];

    int tid = threadIdx.x;
    int n0 = blockIdx.x * 64;

    for (int idx = tid; idx < 64 * FMC; idx += THREADS) {
        int r = idx / FMC, i2 = idx - r * FMC;
        sFM[r * 20 + i2] = fm[n0 * FMC + idx];
    }
    if (tid < 64) {
        int n = n0 + tid;
        int bb = n >> 14, tt = n & 16383, I = tt >> 7, J = tt & 127;
        int s = ((I & 1) << 1) | (J & 1);
        int p = ((I >> 1) << 6) | (J >> 1);
        sOB[tid] = W_OFF + ((bb * 4 + s) * 4096 + p) * Mm;
    }
    __syncthreads();

    // GEMM1: thread tid computes hdn[r][k=tid] for all 64 rows -> sA bf16
    {
        float wreg[FMC];
        #pragma unroll
        for (int i = 0; i < FMC; ++i) wreg[i] = w1g[tid * FMC + i];
        float bj = b1g[tid];
        int g = (tid >> 3) & 7;                       // bank-rotation group
        int base = (tid >> 3) * 512 + (tid & 7);      // short index
        for (int rr = 0; rr < 64; ++rr) {
            int r = (rr + g) & 63;
            const float* fr = sFM + r * 20;
            f32x4 x0 = *(const f32x4*)fr;
            f32x4 x1 = *(const f32x4*)(fr + 4);
            f32x4 x2 = *(const f32x4*)(fr + 8);
            f32x4 x3 = *(const f32x4*)(fr + 12);
            float s = fmaf(fr[16], wreg[16], bj);
            s = fmaf(x0[0], wreg[0], s);  s = fmaf(x0[1], wreg[1], s);
            s = fmaf(x0[2], wreg[2], s);  s = fmaf(x0[3], wreg[3], s);
            s = fmaf(x1[0], wreg[4], s);  s = fmaf(x1[1], wreg[5], s);
            s = fmaf(x1[2], wreg[6], s);  s = fmaf(x1[3], wreg[7], s);
            s = fmaf(x2[0], wreg[8], s);  s = fmaf(x2[1], wreg[9], s);
            s = fmaf(x2[2], wreg[10], s); s = fmaf(x2[3], wreg[11], s);
            s = fmaf(x3[0], wreg[12], s); s = fmaf(x3[1], wreg[13], s);
            s = fmaf(x3[2], wreg[14], s); s = fmaf(x3[3], wreg[15], s);
            sA[base + r * 8] = f2bf(fmaxf(s, 0.f));
        }
    }
    __syncthreads();

    int wid = tid >> 6, l = tid & 63;
    int lm = l & 15, lg = l >> 4;

    int rowbase[4][4];
    #pragma unroll
    for (int rt = 0; rt < 4; ++rt)
        #pragma unroll
        for (int r = 0; r < 4; ++r)
            rowbase[rt][r] = sOB[rt * 16 + lg * 4 + r];

    const short* aptr = sA + lg * 512 + lm * 8;
    const short* bptr = wB + lm * 256 + lg * 8;

    for (int mc = wid; mc < 27; mc += 4) {
        int m0 = mc * 64;
        f32x4 acc[4][4];
        #pragma unroll
        for (int ct = 0; ct < 4; ++ct) {
            float bias = b2g[m0 + ct * 16 + lm];
            #pragma unroll
            for (int rt = 0; rt < 4; ++rt)
                acc[rt][ct] = (f32x4){bias, bias, bias, bias};
        }
        const short* bp0 = bptr + m0 * HID;
        #pragma unroll 2
        for (int s = 0; s < 8; ++s) {
            bf16x8 af[4], bfr[4];
            #pragma unroll
            for (int rt = 0; rt < 4; ++rt)
                af[rt] = *(const bf16x8*)(aptr + s * 2048 + rt * 128);
            #pragma unroll
            for (int ct = 0; ct < 4; ++ct)
                bfr[ct] = *(const bf16x8*)(bp0 + ct * 16 * HID + s * 32);
            #pragma unroll
            for (int rt = 0; rt < 4; ++rt)
                #pragma unroll
                for (int ct = 0; ct < 4; ++ct)
                    acc[rt][ct] = __builtin_amdgcn_mfma_f32_16x16x32_bf16(
                        af[rt], bfr[ct], acc[rt][ct], 0, 0, 0);
        }
        #pragma unroll
        for (int rt = 0; rt < 4; ++rt)
            #pragma unroll
            for (int ct = 0; ct < 4; ++ct) {
                int cb = m0 + ct * 16 + lm;
                #pragma unroll
                for (int r = 0; r < 4; ++r)
                    dout[rowbase[rt][r] + cb] = acc[rt][ct][r];
            }
    }
}

// ---------------- K5: out[b,o,I,J] = sum_k cols[b,p,k] * w_row[k*3+o] --------
__global__ __launch_bounds__(THREADS) void k5_out(const float* __restrict__ x0g,
                                                  float* __restrict__ dout) {
    int tid = threadIdx.x;
    int lane = tid & 63;
    int n = blockIdx.x * 4 + (tid >> 6);
    int bb = n >> 14, tt = n & 16383, I = tt >> 7, J = tt & 127;
    int i = I >> 1, j = J >> 1;
    int s = ((I & 1) << 1) | (J & 1);
    int p = (i << 6) | j;
    const float* wrow = dout + W_OFF + (size_t)((bb * 4 + s) * 4096 + p) * Mm;
    const float* x0b = x0g + bb * 64 * 4096;
    float a0 = 0.f, a1 = 0.f, a2 = 0.f;
    #pragma unroll
    for (int q = 0; q < 9; ++q) {
        int kk = lane + q * 64;
        int c = kk / 9, rem = kk - c * 9;
        int ki = rem / 3, kj = rem - ki * 3;
        int y = i + ki - 1, x = j + kj - 1;
        float val = 0.f;
        if ((unsigned)y < 64u && (unsigned)x < 64u) val = x0b[(c * 64 + y) * 64 + x];
        const float* wp = wrow + kk * 3;
        a0 = fmaf(val, wp[0], a0);
        a1 = fmaf(val, wp[1], a1);
        a2 = fmaf(val, wp[2], a2);
    }
    #pragma unroll
    for (int off = 32; off > 0; off >>= 1) {
        a0 += __shfl_down(a0, off, 64);
        a1 += __shfl_down(a1, off, 64);
        a2 += __shfl_down(a2, off, 64);
    }
    if (lane == 0) {
        int base = bb * 3 * HWp + I * 128 + J;
        dout[base]           = a0;
        dout[base + HWp]     = a1;
        dout[base + 2 * HWp] = a2;
    }
}

extern "C" void kernel_launch(void* const* d_in, const int* in_sizes, int n_in,
                              void* d_out, int out_size, void* d_ws, size_t ws_size,
                              hipStream_t stream) {
    const float* x0      = (const float*)d_in[0];
    const float* feature = (const float*)d_in[1];
    const float* pos     = (const float*)d_in[2];
    const float* w1      = (const float*)d_in[4];
    const float* b1      = (const float*)d_in[5];
    const float* w2      = (const float*)d_in[6];
    const float* b2      = (const float*)d_in[7];
    const float* f2w1_w  = (const float*)d_in[8];
    const float* f2w1_b  = (const float*)d_in[9];
    const float* f2w2_w  = (const float*)d_in[10];
    const float* f2w2_b  = (const float*)d_in[11];

    float* out = (float*)d_out;
    float* ws  = (float*)d_ws;
    float* f1  = ws + F1_OFF;
    float* fm  = ws + FM_OFF;
    short* wB  = (short*)(ws + F1_OFF);   // reuse F1 region after k2

    k1_conv1<<<(Bsz * 16 * 64 * 64) / THREADS, THREADS, 0, stream>>>(feature, w1, b1, f1);
    k2_conv2_fm<<<(Bsz * FMC * HWp) / THREADS, THREADS, 0, stream>>>(f1, w2, b2, pos, fm);
    k3_cvtB<<<(Mm * HID + THREADS - 1) / THREADS, THREADS, 0, stream>>>(f2w2_w, wB);
    k4_gemm<<<Ntot / 64, THREADS, 0, stream>>>(fm, f2w1_w, f2w1_b, wB, f2w2_b, out);
    k5_out<<<Ntot / 4, THREADS, 0, stream>>>(x0, out);
}

// Round 4
// 159.039 us; speedup vs baseline: 8.7522x; 1.1154x over previous
//
#include <hip/hip_runtime.h>

#define THREADS 256

// problem sizes
#define Bsz 2
#define HWp 16384          // 128*128
#define Ntot (Bsz*HWp)     // 32768
#define HID 256
#define Mm 1728
#define FMC 17
#define W_OFF 98304        // 'out' elements precede 'weights' in d_out

// ws layout (in floats)
#define F1_OFF  16384                       // relu(conv1): 2*16*128*128 floats
#define F1_SZ   (Bsz*16*HWp)
#define FM_OFF  (F1_OFF + F1_SZ)            // fm rows: 32768*17 floats
// after k2, the F1 region is dead -> reuse it for bf16 B (1728*256*2 B)

typedef __attribute__((ext_vector_type(8))) short bf16x8;
typedef __attribute__((ext_vector_type(4))) float f32x4;

static __device__ __forceinline__ short f2bf(float x) {
    unsigned u = __builtin_bit_cast(unsigned, x);
    unsigned r = (u + 0x7fff + ((u >> 16) & 1)) >> 16;
    return (short)r;
}

// ---------------- K1: conv1 on upsampled feature + relu ----------------
__global__ __launch_bounds__(THREADS) void k1_conv1(const float* __restrict__ feat,
                                                    const float* __restrict__ w1,
                                                    const float* __restrict__ b1,
                                                    float* __restrict__ f1) {
    __shared__ float sW[4 * 64 * 4];   // [pp][ic][u*2+v]
    int tid = threadIdx.x;
    int t = blockIdx.x * THREADS + tid;
    int c = t & 63, r = (t >> 6) & 63, oc = (t >> 12) & 15, bb = t >> 16;

    #pragma unroll
    for (int q = 0; q < 4; ++q) {
        int e = tid * 4 + q;
        int v = e & 1, u = (e >> 1) & 1, ic = (e >> 2) & 63, pp = (e >> 8) & 3;
        int pi = pp >> 1, pj = pp & 1;
        float s = 0.f;
        for (int ki = 0; ki < 3; ++ki) {
            bool okki = pi ? (u ? (ki == 2) : (ki <= 1)) : (u ? (ki >= 1) : (ki == 0));
            if (!okki) continue;
            for (int kj = 0; kj < 3; ++kj) {
                bool okkj = pj ? (v ? (kj == 2) : (kj <= 1)) : (v ? (kj >= 1) : (kj == 0));
                if (okkj) s += w1[((oc * 64 + ic) * 3 + ki) * 3 + kj];
            }
        }
        sW[(pp * 64 + ic) * 4 + u * 2 + v] = s;
    }
    __syncthreads();

    float bias = b1[oc];
    float acc00 = bias, acc01 = bias, acc10 = bias, acc11 = bias;

    float my0 = (r > 0) ? 1.f : 0.f, my2 = (r < 63) ? 1.f : 0.f;
    float mx0 = (c > 0) ? 1.f : 0.f, mx2 = (c < 63) ? 1.f : 0.f;
    float m00 = my0 * mx0, m01 = my0, m02 = my0 * mx2;
    float m10 = mx0,       m12 = mx2;
    float m20 = my2 * mx0, m21 = my2, m22 = my2 * mx2;
    int ro0 = (r > 0) ? -64 : 0, ro2 = (r < 63) ? 64 : 0;
    int co0 = (c > 0) ? -1 : 0,  co2 = (c < 63) ? 1 : 0;

    const float* fb = feat + bb * 64 * 4096 + r * 64 + c;
    for (int ic = 0; ic < 64; ++ic) {
        const float* p1 = fb + ic * 4096;
        const float* p0 = p1 + ro0;
        const float* p2 = p1 + ro2;
        float v00 = p0[co0] * m00, v01 = p0[0] * m01, v02 = p0[co2] * m02;
        float v10 = p1[co0] * m10, v11 = p1[0],       v12 = p1[co2] * m12;
        float v20 = p2[co0] * m20, v21 = p2[0] * m21, v22 = p2[co2] * m22;

        f32x4 w0 = *(const f32x4*)(sW + (0 * 64 + ic) * 4);
        f32x4 w1v = *(const f32x4*)(sW + (1 * 64 + ic) * 4);
        f32x4 w2v = *(const f32x4*)(sW + (2 * 64 + ic) * 4);
        f32x4 w3 = *(const f32x4*)(sW + (3 * 64 + ic) * 4);

        acc00 = fmaf(w0[0], v00, acc00); acc00 = fmaf(w0[1], v01, acc00);
        acc00 = fmaf(w0[2], v10, acc00); acc00 = fmaf(w0[3], v11, acc00);
        acc01 = fmaf(w1v[0], v01, acc01); acc01 = fmaf(w1v[1], v02, acc01);
        acc01 = fmaf(w1v[2], v11, acc01); acc01 = fmaf(w1v[3], v12, acc01);
        acc10 = fmaf(w2v[0], v10, acc10); acc10 = fmaf(w2v[1], v11, acc10);
        acc10 = fmaf(w2v[2], v20, acc10); acc10 = fmaf(w2v[3], v21, acc10);
        acc11 = fmaf(w3[0], v11, acc11); acc11 = fmaf(w3[1], v12, acc11);
        acc11 = fmaf(w3[2], v21, acc11); acc11 = fmaf(w3[3], v22, acc11);
    }

    float* fo = f1 + (bb * 16 + oc) * HWp + (2 * r) * 128 + 2 * c;
    float2 r0 = make_float2(fmaxf(acc00, 0.f), fmaxf(acc01, 0.f));
    float2 r1 = make_float2(fmaxf(acc10, 0.f), fmaxf(acc11, 0.f));
    *reinterpret_cast<float2*>(fo) = r0;
    *reinterpret_cast<float2*>(fo + 128) = r1;
}

// ---------------- K2: conv2 -> fm rows (ch16 = pos plane 0) ----------------
__global__ __launch_bounds__(THREADS) void k2_conv2_fm(const float* __restrict__ f1,
                                                       const float* __restrict__ w2,
                                                       const float* __restrict__ b2,
                                                       const float* __restrict__ pos,
                                                       float* __restrict__ fm) {
    int t = blockIdx.x * THREADS + threadIdx.x;
    if (t >= Bsz * FMC * HWp) return;
    int J = t & 127, I = (t >> 7) & 127;
    int bc = t >> 14;
    int ch = bc % FMC, bb = bc / FMC;
    int n = bb * HWp + I * 128 + J;
    float val;
    if (ch == 16) {
        val = pos[(I * 128 + J) * 3];
    } else {
        float acc = b2[ch];
        for (int ic = 0; ic < 16; ++ic) {
            const float* fb = f1 + (bb * 16 + ic) * HWp;
            const float* wb = w2 + (ch * 16 + ic) * 9;
            for (int ki = 0; ki < 3; ++ki) {
                int y = I + ki - 1;
                if ((unsigned)y >= 128u) continue;
                const float* row = fb + y * 128;
                for (int kj = 0; kj < 3; ++kj) {
                    int x = J + kj - 1;
                    if ((unsigned)x >= 128u) continue;
                    acc = fmaf(row[x], wb[ki * 3 + kj], acc);
                }
            }
        }
        val = acc;
    }
    fm[n * FMC + ch] = val;
}

// ---------------- K3: f2w2_w (1728x256 fp32) -> bf16 in fragment-major -----
// wB2[(((mc*8+s)*4+ct)*64 + l)*8 + i] = bf16(w2g[(mc*64+ct*16+(l&15))*256
//                                              + s*32 + (l>>4)*8 + i])
__global__ __launch_bounds__(THREADS) void k3_cvtB(const float* __restrict__ w2g,
                                                   short* __restrict__ wB2) {
    int t = blockIdx.x * THREADS + threadIdx.x;
    int i = t & 7, l = (t >> 3) & 63, ct = (t >> 9) & 3, s = (t >> 11) & 7, mc = t >> 14;
    int col = mc * 64 + ct * 16 + (l & 15);
    int k = s * 32 + (l >> 4) * 8 + i;
    wB2[t] = f2bf(w2g[col * HID + k]);
}

// ---------------- K4: fused GEMM1(+relu) + bf16-MFMA GEMM2 ----------------
__global__ __launch_bounds__(THREADS) void k4_gemm(const float* __restrict__ fm,
                                                   const float* __restrict__ w1g,
                                                   const float* __restrict__ b1g,
                                                   const short* __restrict__ wB2,
                                                   const float* __restrict__ b2g,
                                                   float* __restrict__ dout) {
    // sA layout (shorts): element (row,k) at ((k>>3)*64 + row)*8 + (k&7)
    __shared__ short sA[16384];       // 32 KB
    __shared__ float sFM[64 * 20];    // padded stride 20
    __shared__ int   sOB[64];

    int tid = threadIdx.x;
    int n0 = blockIdx.x * 64;

    for (int idx = tid; idx < 64 * FMC; idx += THREADS) {
        int r = idx / FMC, i2 = idx - r * FMC;
        sFM[r * 20 + i2] = fm[n0 * FMC + idx];
    }
    if (tid < 64) {
        int n = n0 + tid;
        int bb = n >> 14, tt = n & 16383, I = tt >> 7, J = tt & 127;
        int s = ((I & 1) << 1) | (J & 1);
        int p = ((I >> 1) << 6) | (J >> 1);
        sOB[tid] = W_OFF + ((bb * 4 + s) * 4096 + p) * Mm;
    }
    __syncthreads();

    // GEMM1: thread tid computes hdn[r][k=tid] for all 64 rows -> sA bf16
    {
        float wreg[FMC];
        #pragma unroll
        for (int i = 0; i < FMC; ++i) wreg[i] = w1g[tid * FMC + i];
        float bj = b1g[tid];
        int g = (tid >> 3) & 7;                       // bank-rotation group
        int base = (tid >> 3) * 512 + (tid & 7);      // short index
        for (int rr = 0; rr < 64; ++rr) {
            int r = (rr + g) & 63;
            const float* fr = sFM + r * 20;
            f32x4 x0 = *(const f32x4*)fr;
            f32x4 x1 = *(const f32x4*)(fr + 4);
            f32x4 x2 = *(const f32x4*)(fr + 8);
            f32x4 x3 = *(const f32x4*)(fr + 12);
            float s = fmaf(fr[16], wreg[16], bj);
            s = fmaf(x0[0], wreg[0], s);  s = fmaf(x0[1], wreg[1], s);
            s = fmaf(x0[2], wreg[2], s);  s = fmaf(x0[3], wreg[3], s);
            s = fmaf(x1[0], wreg[4], s);  s = fmaf(x1[1], wreg[5], s);
            s = fmaf(x1[2], wreg[6], s);  s = fmaf(x1[3], wreg[7], s);
            s = fmaf(x2[0], wreg[8], s);  s = fmaf(x2[1], wreg[9], s);
            s = fmaf(x2[2], wreg[10], s); s = fmaf(x2[3], wreg[11], s);
            s = fmaf(x3[0], wreg[12], s); s = fmaf(x3[1], wreg[13], s);
            s = fmaf(x3[2], wreg[14], s); s = fmaf(x3[3], wreg[15], s);
            sA[base + r * 8] = f2bf(fmaxf(s, 0.f));
        }
    }
    __syncthreads();

    int wid = tid >> 6, l = tid & 63;
    int lm = l & 15, lg = l >> 4;

    int rowbase[4][4];
    #pragma unroll
    for (int rt = 0; rt < 4; ++rt)
        #pragma unroll
        for (int r = 0; r < 4; ++r)
            rowbase[rt][r] = sOB[rt * 16 + lg * 4 + r];

    const short* aptr = sA + lg * 512 + lm * 8;

    for (int mc = wid; mc < 27; mc += 4) {
        int m0 = mc * 64;
        f32x4 acc[4][4];
        #pragma unroll
        for (int ct = 0; ct < 4; ++ct) {
            float bias = b2g[m0 + ct * 16 + lm];
            #pragma unroll
            for (int rt = 0; rt < 4; ++rt)
                acc[rt][ct] = (f32x4){bias, bias, bias, bias};
        }
        // fragment-major B: contiguous 1 KB per (s,ct) load
        const short* bbase = wB2 + (size_t)mc * 16384 + l * 8;
        #pragma unroll 2
        for (int s = 0; s < 8; ++s) {
            bf16x8 af[4], bfr[4];
            #pragma unroll
            for (int rt = 0; rt < 4; ++rt)
                af[rt] = *(const bf16x8*)(aptr + s * 2048 + rt * 128);
            #pragma unroll
            for (int ct = 0; ct < 4; ++ct)
                bfr[ct] = *(const bf16x8*)(bbase + (s * 4 + ct) * 512);
            #pragma unroll
            for (int rt = 0; rt < 4; ++rt)
                #pragma unroll
                for (int ct = 0; ct < 4; ++ct)
                    acc[rt][ct] = __builtin_amdgcn_mfma_f32_16x16x32_bf16(
                        af[rt], bfr[ct], acc[rt][ct], 0, 0, 0);
        }
        #pragma unroll
        for (int rt = 0; rt < 4; ++rt)
            #pragma unroll
            for (int ct = 0; ct < 4; ++ct) {
                int cb = m0 + ct * 16 + lm;
                #pragma unroll
                for (int r = 0; r < 4; ++r)
                    dout[rowbase[rt][r] + cb] = acc[rt][ct][r];
            }
    }
}

// ---------------- K5: block = 64 pixels; x0 slab + LUT in LDS; f4 reads -----
__global__ __launch_bounds__(THREADS) void k5_out(const float* __restrict__ x0g,
                                                  float* __restrict__ dout) {
    __shared__ float    sX[6528];      // [64ch][3ki][34cols], zero-padded
    __shared__ unsigned sLUT[1728];    // m -> (ch*3+ki)*34 + kj

    int tid = threadIdx.x;
    int n0 = blockIdx.x * 64;
    int bb = n0 >> 14, tt = n0 & 16383, I = tt >> 7, J0 = tt & 127;
    int i = I >> 1, jmin = J0 >> 1;

    for (int m = tid; m < Mm; m += THREADS) {
        int k = m / 3;
        int ch = k / 9, rem = k - ch * 9;
        int ki = rem / 3, kj = rem - ki * 3;
        sLUT[m] = (unsigned)((ch * 3 + ki) * 34 + kj);
    }
    const float* x0b = x0g + bb * 64 * 4096;
    for (int e = tid; e < 6528; e += THREADS) {
        int ch = e / 102, r2 = e - ch * 102;
        int ki = r2 / 34, jc = r2 - ki * 34;
        int y = i + ki - 1, x = jmin + jc - 1;
        float v = 0.f;
        if ((unsigned)y < 64u && (unsigned)x < 64u) v = x0b[(ch * 64 + y) * 64 + x];
        sX[e] = v;
    }
    __syncthreads();

    int wid = tid >> 6, lane = tid & 63;
    int lm3 = lane % 3;

    for (int pp = 0; pp < 16; ++pp) {
        int pr = wid * 16 + pp;
        int s = ((I & 1) << 1) | (pr & 1);
        int jloc = pr >> 1;
        int p = i * 64 + jmin + jloc;
        const float* wrow = dout + W_OFF + (size_t)((bb * 4 + s) * 4096 + p) * Mm;

        float r0 = 0.f, r1 = 0.f, r2 = 0.f;
        #pragma unroll
        for (int it = 0; it < 7; ++it) {
            if (it < 6 || lane < 48) {
                int m = it * 256 + lane * 4;
                float4 wv = *(const float4*)(wrow + m);
                uint4 lt = *(const uint4*)(sLUT + m);
                float c0 = sX[lt.x + jloc], c1 = sX[lt.y + jloc];
                float c2 = sX[lt.z + jloc], c3 = sX[lt.w + jloc];
                // o = (lane + it + e) mod 3 ; q = (it+e)%3 is compile-time
                float p0 = fmaf(c0, wv.x, c3 * wv.w);
                float p1 = c1 * wv.y;
                float p2 = c2 * wv.z;
                switch (it % 3) {
                    case 0: r0 += p0; r1 += p1; r2 += p2; break;
                    case 1: r1 += p0; r2 += p1; r0 += p2; break;
                    default: r2 += p0; r0 += p1; r1 += p2; break;
                }
            }
        }
        // un-rotate: o = (lm3 + q) mod 3
        float a0 = (lm3 == 0) ? r0 : ((lm3 == 1) ? r2 : r1);
        float a1 = (lm3 == 0) ? r1 : ((lm3 == 1) ? r0 : r2);
        float a2 = (lm3 == 0) ? r2 : ((lm3 == 1) ? r1 : r0);
        #pragma unroll
        for (int off = 32; off > 0; off >>= 1) {
            a0 += __shfl_xor(a0, off, 64);
            a1 += __shfl_xor(a1, off, 64);
            a2 += __shfl_xor(a2, off, 64);
        }
        if (lane == 0) {
            int base = bb * 3 * HWp + I * 128 + J0 + pr;
            dout[base]           = a0;
            dout[base + HWp]     = a1;
            dout[base + 2 * HWp] = a2;
        }
    }
}

extern "C" void kernel_launch(void* const* d_in, const int* in_sizes, int n_in,
                              void* d_out, int out_size, void* d_ws, size_t ws_size,
                              hipStream_t stream) {
    const float* x0      = (const float*)d_in[0];
    const float* feature = (const float*)d_in[1];
    const float* pos     = (const float*)d_in[2];
    const float* w1      = (const float*)d_in[4];
    const float* b1      = (const float*)d_in[5];
    const float* w2      = (const float*)d_in[6];
    const float* b2      = (const float*)d_in[7];
    const float* f2w1_w  = (const float*)d_in[8];
    const float* f2w1_b  = (const float*)d_in[9];
    const float* f2w2_w  = (const float*)d_in[10];
    const float* f2w2_b  = (const float*)d_in[11];

    float* out = (float*)d_out;
    float* ws  = (float*)d_ws;
    float* f1  = ws + F1_OFF;
    float* fm  = ws + FM_OFF;
    short* wB2 = (short*)(ws + F1_OFF);   // reuse F1 region after k2

    k1_conv1<<<(Bsz * 16 * 64 * 64) / THREADS, THREADS, 0, stream>>>(feature, w1, b1, f1);
    k2_conv2_fm<<<(Bsz * FMC * HWp) / THREADS, THREADS, 0, stream>>>(f1, w2, b2, pos, fm);
    k3_cvtB<<<(Mm * HID) / THREADS, THREADS, 0, stream>>>(f2w2_w, wB2);
    k4_gemm<<<Ntot / 64, THREADS, 0, stream>>>(fm, f2w1_w, f2w1_b, wB2, f2w2_b, out);
    k5_out<<<Ntot / 64, THREADS, 0, stream>>>(x0, out);
}

// Round 5
// 126.785 us; speedup vs baseline: 10.9787x; 1.2544x over previous
//
#include <hip/hip_runtime.h>

#define THREADS 256

// problem sizes
#define Bsz 2
#define HWp 16384          // 128*128
#define Ntot (Bsz*HWp)     // 32768
#define HID 256
#define Mm 1728
#define FMC 17
#define W_OFF 98304        // 'out' elements precede 'weights' in d_out

// ws layout (in floats)
#define F1_OFF  16384                       // relu(conv1): 2*16*128*128 floats
#define F1_SZ   (Bsz*16*HWp)
#define FM_OFF  (F1_OFF + F1_SZ)            // fm rows: 32768*17 floats
// after k2, the F1 region is dead -> reuse it for bf16 B (1728*256*2 B)

typedef __attribute__((ext_vector_type(8))) short bf16x8;
typedef __attribute__((ext_vector_type(4))) float f32x4;

static __device__ __forceinline__ short f2bf(float x) {
    unsigned u = __builtin_bit_cast(unsigned, x);
    unsigned r = (u + 0x7fff + ((u >> 16) & 1)) >> 16;
    return (short)r;
}

// ---------------- K1: conv1 on upsampled feature + relu ----------------
__global__ __launch_bounds__(THREADS) void k1_conv1(const float* __restrict__ feat,
                                                    const float* __restrict__ w1,
                                                    const float* __restrict__ b1,
                                                    float* __restrict__ f1) {
    __shared__ float sW[4 * 64 * 4];   // [pp][ic][u*2+v]
    int tid = threadIdx.x;
    int t = blockIdx.x * THREADS + tid;
    int c = t & 63, r = (t >> 6) & 63, oc = (t >> 12) & 15, bb = t >> 16;

    #pragma unroll
    for (int q = 0; q < 4; ++q) {
        int e = tid * 4 + q;
        int v = e & 1, u = (e >> 1) & 1, ic = (e >> 2) & 63, pp = (e >> 8) & 3;
        int pi = pp >> 1, pj = pp & 1;
        float s = 0.f;
        for (int ki = 0; ki < 3; ++ki) {
            bool okki = pi ? (u ? (ki == 2) : (ki <= 1)) : (u ? (ki >= 1) : (ki == 0));
            if (!okki) continue;
            for (int kj = 0; kj < 3; ++kj) {
                bool okkj = pj ? (v ? (kj == 2) : (kj <= 1)) : (v ? (kj >= 1) : (kj == 0));
                if (okkj) s += w1[((oc * 64 + ic) * 3 + ki) * 3 + kj];
            }
        }
        sW[(pp * 64 + ic) * 4 + u * 2 + v] = s;
    }
    __syncthreads();

    float bias = b1[oc];
    float acc00 = bias, acc01 = bias, acc10 = bias, acc11 = bias;

    float my0 = (r > 0) ? 1.f : 0.f, my2 = (r < 63) ? 1.f : 0.f;
    float mx0 = (c > 0) ? 1.f : 0.f, mx2 = (c < 63) ? 1.f : 0.f;
    float m00 = my0 * mx0, m01 = my0, m02 = my0 * mx2;
    float m10 = mx0,       m12 = mx2;
    float m20 = my2 * mx0, m21 = my2, m22 = my2 * mx2;
    int ro0 = (r > 0) ? -64 : 0, ro2 = (r < 63) ? 64 : 0;
    int co0 = (c > 0) ? -1 : 0,  co2 = (c < 63) ? 1 : 0;

    const float* fb = feat + bb * 64 * 4096 + r * 64 + c;
    for (int ic = 0; ic < 64; ++ic) {
        const float* p1 = fb + ic * 4096;
        const float* p0 = p1 + ro0;
        const float* p2 = p1 + ro2;
        float v00 = p0[co0] * m00, v01 = p0[0] * m01, v02 = p0[co2] * m02;
        float v10 = p1[co0] * m10, v11 = p1[0],       v12 = p1[co2] * m12;
        float v20 = p2[co0] * m20, v21 = p2[0] * m21, v22 = p2[co2] * m22;

        f32x4 w0 = *(const f32x4*)(sW + (0 * 64 + ic) * 4);
        f32x4 w1v = *(const f32x4*)(sW + (1 * 64 + ic) * 4);
        f32x4 w2v = *(const f32x4*)(sW + (2 * 64 + ic) * 4);
        f32x4 w3 = *(const f32x4*)(sW + (3 * 64 + ic) * 4);

        acc00 = fmaf(w0[0], v00, acc00); acc00 = fmaf(w0[1], v01, acc00);
        acc00 = fmaf(w0[2], v10, acc00); acc00 = fmaf(w0[3], v11, acc00);
        acc01 = fmaf(w1v[0], v01, acc01); acc01 = fmaf(w1v[1], v02, acc01);
        acc01 = fmaf(w1v[2], v11, acc01); acc01 = fmaf(w1v[3], v12, acc01);
        acc10 = fmaf(w2v[0], v10, acc10); acc10 = fmaf(w2v[1], v11, acc10);
        acc10 = fmaf(w2v[2], v20, acc10); acc10 = fmaf(w2v[3], v21, acc10);
        acc11 = fmaf(w3[0], v11, acc11); acc11 = fmaf(w3[1], v12, acc11);
        acc11 = fmaf(w3[2], v21, acc11); acc11 = fmaf(w3[3], v22, acc11);
    }

    float* fo = f1 + (bb * 16 + oc) * HWp + (2 * r) * 128 + 2 * c;
    float2 r0 = make_float2(fmaxf(acc00, 0.f), fmaxf(acc01, 0.f));
    float2 r1 = make_float2(fmaxf(acc10, 0.f), fmaxf(acc11, 0.f));
    *reinterpret_cast<float2*>(fo) = r0;
    *reinterpret_cast<float2*>(fo + 128) = r1;
}

// ---------------- K2: conv2 -> fm rows (ch16 = pos plane 0) ----------------
__global__ __launch_bounds__(THREADS) void k2_conv2_fm(const float* __restrict__ f1,
                                                       const float* __restrict__ w2,
                                                       const float* __restrict__ b2,
                                                       const float* __restrict__ pos,
                                                       float* __restrict__ fm) {
    int t = blockIdx.x * THREADS + threadIdx.x;
    if (t >= Bsz * FMC * HWp) return;
    int J = t & 127, I = (t >> 7) & 127;
    int bc = t >> 14;
    int ch = bc % FMC, bb = bc / FMC;
    int n = bb * HWp + I * 128 + J;
    float val;
    if (ch == 16) {
        val = pos[(I * 128 + J) * 3];
    } else {
        float acc = b2[ch];
        for (int ic = 0; ic < 16; ++ic) {
            const float* fb = f1 + (bb * 16 + ic) * HWp;
            const float* wb = w2 + (ch * 16 + ic) * 9;
            for (int ki = 0; ki < 3; ++ki) {
                int y = I + ki - 1;
                if ((unsigned)y >= 128u) continue;
                const float* row = fb + y * 128;
                for (int kj = 0; kj < 3; ++kj) {
                    int x = J + kj - 1;
                    if ((unsigned)x >= 128u) continue;
                    acc = fmaf(row[x], wb[ki * 3 + kj], acc);
                }
            }
        }
        val = acc;
    }
    fm[n * FMC + ch] = val;
}

// ---------------- K3: f2w2_w (1728x256 fp32) -> bf16 in fragment-major -----
__global__ __launch_bounds__(THREADS) void k3_cvtB(const float* __restrict__ w2g,
                                                   short* __restrict__ wB2) {
    int t = blockIdx.x * THREADS + threadIdx.x;
    int i = t & 7, l = (t >> 3) & 63, ct = (t >> 9) & 3, s = (t >> 11) & 7, mc = t >> 14;
    int col = mc * 64 + ct * 16 + (l & 15);
    int k = s * 32 + (l >> 4) * 8 + i;
    wB2[t] = f2bf(w2g[col * HID + k]);
}

// ---------------- K4: GEMM1(+relu) + bf16-MFMA GEMM2 + fused einsum out ----
__global__ __launch_bounds__(THREADS, 2) void k4_gemm(const float* __restrict__ fm,
                                                      const float* __restrict__ w1g,
                                                      const float* __restrict__ b1g,
                                                      const short* __restrict__ wB2,
                                                      const float* __restrict__ b2g,
                                                      const float* __restrict__ x0g,
                                                      float* __restrict__ dout) {
    // sA layout (shorts): element (row,k) at ((k>>3)*64 + row)*8 + (k&7)
    __shared__ short    sA[16384];     // 32 KB
    __shared__ float    sFM[64 * 20];  // padded stride 20
    __shared__ int      sOB[64];
    __shared__ float    sX[6528];      // [64ch][3ki][34cols], zero-padded
    __shared__ unsigned sLUT[1728];    // m -> (ch*3+ki)*34 + kj
    __shared__ float    sOut[4 * 64 * 3];

    int tid = threadIdx.x;
    int n0 = blockIdx.x * 64;
    int bb = n0 >> 14, tt = n0 & 16383, I = tt >> 7, J0 = tt & 127;
    int i0 = I >> 1, jmin = J0 >> 1;

    for (int idx = tid; idx < 64 * FMC; idx += THREADS) {
        int r = idx / FMC, i2 = idx - r * FMC;
        sFM[r * 20 + i2] = fm[n0 * FMC + idx];
    }
    if (tid < 64) {
        int n = n0 + tid;
        int J = J0 + tid;
        int s = ((I & 1) << 1) | (J & 1);
        int p = ((I >> 1) << 6) | (J >> 1);
        sOB[tid] = W_OFF + ((bb * 4 + s) * 4096 + p) * Mm;
    }
    // x0 slab + LUT for fused einsum
    for (int m = tid; m < Mm; m += THREADS) {
        int k = m / 3;
        int ch = k / 9, rem = k - ch * 9;
        int ki = rem / 3, kj = rem - ki * 3;
        sLUT[m] = (unsigned)((ch * 3 + ki) * 34 + kj);
    }
    {
        const float* x0b = x0g + bb * 64 * 4096;
        for (int e = tid; e < 6528; e += THREADS) {
            int ch = e / 102, r2 = e - ch * 102;
            int ki = r2 / 34, jc = r2 - ki * 34;
            int y = i0 + ki - 1, x = jmin + jc - 1;
            float v = 0.f;
            if ((unsigned)y < 64u && (unsigned)x < 64u) v = x0b[(ch * 64 + y) * 64 + x];
            sX[e] = v;
        }
    }
    __syncthreads();

    // GEMM1: thread tid computes hdn[r][k=tid] for all 64 rows -> sA bf16
    {
        float wreg[FMC];
        #pragma unroll
        for (int i = 0; i < FMC; ++i) wreg[i] = w1g[tid * FMC + i];
        float bj = b1g[tid];
        int g = (tid >> 3) & 7;                       // bank-rotation group
        int base = (tid >> 3) * 512 + (tid & 7);      // short index
        for (int rr = 0; rr < 64; ++rr) {
            int r = (rr + g) & 63;
            const float* fr = sFM + r * 20;
            f32x4 x0 = *(const f32x4*)fr;
            f32x4 x1 = *(const f32x4*)(fr + 4);
            f32x4 x2 = *(const f32x4*)(fr + 8);
            f32x4 x3 = *(const f32x4*)(fr + 12);
            float s = fmaf(fr[16], wreg[16], bj);
            s = fmaf(x0[0], wreg[0], s);  s = fmaf(x0[1], wreg[1], s);
            s = fmaf(x0[2], wreg[2], s);  s = fmaf(x0[3], wreg[3], s);
            s = fmaf(x1[0], wreg[4], s);  s = fmaf(x1[1], wreg[5], s);
            s = fmaf(x1[2], wreg[6], s);  s = fmaf(x1[3], wreg[7], s);
            s = fmaf(x2[0], wreg[8], s);  s = fmaf(x2[1], wreg[9], s);
            s = fmaf(x2[2], wreg[10], s); s = fmaf(x2[3], wreg[11], s);
            s = fmaf(x3[0], wreg[12], s); s = fmaf(x3[1], wreg[13], s);
            s = fmaf(x3[2], wreg[14], s); s = fmaf(x3[3], wreg[15], s);
            sA[base + r * 8] = f2bf(fmaxf(s, 0.f));
        }
    }
    __syncthreads();

    int wid = tid >> 6, l = tid & 63;
    int lm = l & 15, lg = l >> 4;
    int lm3 = lm % 3;

    int rowbase[4][4];
    #pragma unroll
    for (int rt = 0; rt < 4; ++rt)
        #pragma unroll
        for (int r = 0; r < 4; ++r)
            rowbase[rt][r] = sOB[rt * 16 + lg * 4 + r];

    // jloc (pixel column within slab) for r in {0,1} and {2,3}
    int jl0[4], jl1[4];
    #pragma unroll
    for (int rt = 0; rt < 4; ++rt) {
        jl0[rt] = rt * 8 + lg * 2;      // (rt*16+lg*4+{0,1})>>1
        jl1[rt] = rt * 8 + lg * 2 + 1;  // (rt*16+lg*4+{2,3})>>1
    }

    const short* aptr = sA + lg * 512 + lm * 8;

    float racc[4][4][3];
    #pragma unroll
    for (int rt = 0; rt < 4; ++rt)
        #pragma unroll
        for (int r = 0; r < 4; ++r) {
            racc[rt][r][0] = 0.f; racc[rt][r][1] = 0.f; racc[rt][r][2] = 0.f;
        }

    for (int mc = wid; mc < 27; mc += 4) {
        int m0 = mc * 64;
        f32x4 acc[4][4];
        #pragma unroll
        for (int ct = 0; ct < 4; ++ct) {
            float bias = b2g[m0 + ct * 16 + lm];
            #pragma unroll
            for (int rt = 0; rt < 4; ++rt)
                acc[rt][ct] = (f32x4){bias, bias, bias, bias};
        }
        // fragment-major B: contiguous 1 KB per (s,ct) load
        const short* bbase = wB2 + (size_t)mc * 16384 + l * 8;
        #pragma unroll 2
        for (int s = 0; s < 8; ++s) {
            bf16x8 af[4], bfr[4];
            #pragma unroll
            for (int rt = 0; rt < 4; ++rt)
                af[rt] = *(const bf16x8*)(aptr + s * 2048 + rt * 128);
            #pragma unroll
            for (int ct = 0; ct < 4; ++ct)
                bfr[ct] = *(const bf16x8*)(bbase + (s * 4 + ct) * 512);
            #pragma unroll
            for (int rt = 0; rt < 4; ++rt)
                #pragma unroll
                for (int ct = 0; ct < 4; ++ct)
                    acc[rt][ct] = __builtin_amdgcn_mfma_f32_16x16x32_bf16(
                        af[rt], bfr[ct], acc[rt][ct], 0, 0, 0);
        }
        // store weights
        #pragma unroll
        for (int rt = 0; rt < 4; ++rt)
            #pragma unroll
            for (int ct = 0; ct < 4; ++ct) {
                int cb = m0 + ct * 16 + lm;
                #pragma unroll
                for (int r = 0; r < 4; ++r)
                    dout[rowbase[rt][r] + cb] = acc[rt][ct][r];
            }
        // fused einsum accumulation (rotated-o space; q=(mc+ct)%3 static per case)
        unsigned cidx[4];
        #pragma unroll
        for (int ct = 0; ct < 4; ++ct) cidx[ct] = sLUT[m0 + ct * 16 + lm];
#define ACCUM(QB)                                                              \
        _Pragma("unroll")                                                      \
        for (int ct = 0; ct < 4; ++ct) {                                       \
            _Pragma("unroll")                                                  \
            for (int rt = 0; rt < 4; ++rt) {                                   \
                float v0 = sX[cidx[ct] + jl0[rt]];                             \
                float v1 = sX[cidx[ct] + jl1[rt]];                             \
                racc[rt][0][((QB) + ct) % 3] = fmaf(acc[rt][ct][0], v0,        \
                                racc[rt][0][((QB) + ct) % 3]);                 \
                racc[rt][1][((QB) + ct) % 3] = fmaf(acc[rt][ct][1], v0,        \
                                racc[rt][1][((QB) + ct) % 3]);                 \
                racc[rt][2][((QB) + ct) % 3] = fmaf(acc[rt][ct][2], v1,        \
                                racc[rt][2][((QB) + ct) % 3]);                 \
                racc[rt][3][((QB) + ct) % 3] = fmaf(acc[rt][ct][3], v1,        \
                                racc[rt][3][((QB) + ct) % 3]);                 \
            }                                                                  \
        }
        switch (mc % 3) {
            case 0: ACCUM(0); break;
            case 1: ACCUM(1); break;
            default: ACCUM(2); break;
        }
#undef ACCUM
    }

    // un-rotate (o = (lm3+q)%3), reduce across the 16-lane col group, stash
    #pragma unroll
    for (int rt = 0; rt < 4; ++rt)
        #pragma unroll
        for (int r = 0; r < 4; ++r) {
            float q0 = racc[rt][r][0], q1 = racc[rt][r][1], q2 = racc[rt][r][2];
            float a0 = (lm3 == 0) ? q0 : ((lm3 == 1) ? q2 : q1);
            float a1 = (lm3 == 0) ? q1 : ((lm3 == 1) ? q0 : q2);
            float a2 = (lm3 == 0) ? q2 : ((lm3 == 1) ? q1 : q0);
            #pragma unroll
            for (int off = 8; off > 0; off >>= 1) {
                a0 += __shfl_xor(a0, off, 64);
                a1 += __shfl_xor(a1, off, 64);
                a2 += __shfl_xor(a2, off, 64);
            }
            if (lm == 0) {
                int pix = rt * 16 + lg * 4 + r;
                float* so = sOut + (wid * 64 + pix) * 3;
                so[0] = a0; so[1] = a1; so[2] = a2;
            }
        }
    __syncthreads();
    if (tid < 192) {
        float s = sOut[tid] + sOut[192 + tid] + sOut[384 + tid] + sOut[576 + tid];
        int pix = tid / 3, o = tid - 3 * pix;
        dout[bb * 3 * HWp + o * HWp + I * 128 + J0 + pix] = s;
    }
}

extern "C" void kernel_launch(void* const* d_in, const int* in_sizes, int n_in,
                              void* d_out, int out_size, void* d_ws, size_t ws_size,
                              hipStream_t stream) {
    const float* x0      = (const float*)d_in[0];
    const float* feature = (const float*)d_in[1];
    const float* pos     = (const float*)d_in[2];
    const float* w1      = (const float*)d_in[4];
    const float* b1      = (const float*)d_in[5];
    const float* w2      = (const float*)d_in[6];
    const float* b2      = (const float*)d_in[7];
    const float* f2w1_w  = (const float*)d_in[8];
    const float* f2w1_b  = (const float*)d_in[9];
    const float* f2w2_w  = (const float*)d_in[10];
    const float* f2w2_b  = (const float*)d_in[11];

    float* out = (float*)d_out;
    float* ws  = (float*)d_ws;
    float* f1  = ws + F1_OFF;
    float* fm  = ws + FM_OFF;
    short* wB2 = (short*)(ws + F1_OFF);   // reuse F1 region after k2

    k1_conv1<<<(Bsz * 16 * 64 * 64) / THREADS, THREADS, 0, stream>>>(feature, w1, b1, f1);
    k2_conv2_fm<<<(Bsz * FMC * HWp) / THREADS, THREADS, 0, stream>>>(f1, w2, b2, pos, fm);
    k3_cvtB<<<(Mm * HID) / THREADS, THREADS, 0, stream>>>(f2w2_w, wB2);
    k4_gemm<<<Ntot / 64, THREADS, 0, stream>>>(fm, f2w1_w, f2w1_b, wB2, f2w2_b, x0, out);
}